// Round 2
// baseline (322.884 us; speedup 1.0000x reference)
//
#include <hip/hip_runtime.h>

// AdaptiveConv2d: hypernetwork MLP -> per-sample conv kernels, then
// per-sample 3x3 SAME conv + bias + relu, via bf16 implicit-GEMM MFMA.
//
// R2 changes vs R1:
//  - hyper: threads ordered by output layout -> coalesced bf16 stores
//  - conv: 512-thread blocks (8 waves), single __syncthreads, weights
//    stream global->reg with 1-tap-ahead prefetch (no weight LDS),
//    vectorized x staging (8 coalesced loads -> one 16B LDS store,
//    conflict-free bank groups).

typedef __bf16 bf16;
typedef __bf16 bf16x8 __attribute__((ext_vector_type(8)));
typedef float f32x4 __attribute__((ext_vector_type(4)));

#define NB 16     // batch
#define CI 64
#define CO 64
#define HH 128
#define WW 128
#define TS 16     // spatial tile (TS x TS)
#define HALO 18   // TS + 2
#define CPAD 72   // xt channel stride (16B-aligned, bank-spread)
#define NKW 36864 // CO*CI*9
#define NROWS 36928

// ---------------- hypernetwork ----------------
// aw = relu(h1 @ W2^T + b2); emitted as wt[b][tap][co][ci] (bf16) + biases.
// Thread <-> output element e (ci fastest) so stores are coalesced; each
// thread reads its W2 row (30 floats) once, loops the 16 samples.
__global__ __launch_bounds__(256)
void hyper_kernel(const float* __restrict__ z, const float* __restrict__ W0,
                  const float* __restrict__ b0, const float* __restrict__ W1,
                  const float* __restrict__ b1, const float* __restrict__ W2,
                  const float* __restrict__ b2, bf16* __restrict__ wt,
                  float* __restrict__ biases) {
  __shared__ float h1s[NB][30];
  const int tid = threadIdx.x;
  if (tid < NB) {
    float h0[20];
    #pragma unroll
    for (int i = 0; i < 20; ++i) {
      float s = b0[i];
      #pragma unroll
      for (int j = 0; j < 16; ++j) s += W0[i * 16 + j] * z[tid * 16 + j];
      h0[i] = fmaxf(s, 0.f);
    }
    #pragma unroll
    for (int i = 0; i < 30; ++i) {
      float s = b1[i];
      #pragma unroll
      for (int j = 0; j < 20; ++j) s += W1[i * 20 + j] * h0[j];
      h1s[tid][i] = fmaxf(s, 0.f);
    }
  }
  __syncthreads();

  if (blockIdx.x < 144) {
    // kernel weights: e in [0, 36864), layout order (tap, co, ci)
    const int e = blockIdx.x * 256 + tid;
    const int tap = e >> 12;           // e / 4096
    const int rem = e & 4095;
    const int co = rem >> 6;
    const int ci = rem & 63;
    const int r = co * 576 + ci * 9 + tap;  // W2 row
    float w2r[30];
    #pragma unroll
    for (int j = 0; j < 30; ++j) w2r[j] = W2[r * 30 + j];
    const float bb = b2[r];
    for (int b = 0; b < NB; ++b) {
      float s = bb;
      #pragma unroll
      for (int j = 0; j < 30; ++j) s += w2r[j] * h1s[b][j];
      wt[(size_t)b * NKW + e] = (bf16)fmaxf(s, 0.f);
    }
  } else {
    // biases: 64 rows
    if (tid < CO) {
      const int r = NKW + tid;
      float w2r[30];
      #pragma unroll
      for (int j = 0; j < 30; ++j) w2r[j] = W2[r * 30 + j];
      const float bb = b2[r];
      for (int b = 0; b < NB; ++b) {
        float s = bb;
        #pragma unroll
        for (int j = 0; j < 30; ++j) s += w2r[j] * h1s[b][j];
        biases[b * CO + tid] = fmaxf(s, 0.f);
      }
    }
  }
}

// ---------------- conv (implicit GEMM, bf16 MFMA) ----------------
// block: 1 sample x 16x16 spatial tile x all 64 co, 512 threads = 8 waves.
// Wave w: co-group cg = w&3 (16 co), pixel rows ty0 = (w>>2)*8 .. +8.
// Weights stream from global (L2-hot) with 1-tap-ahead prefetch; x tile
// staged once in LDS as [pixel][ci] bf16 (pad 72). One barrier per block.
__global__ __launch_bounds__(512, 4)
void conv_kernel(const float* __restrict__ x, const bf16* __restrict__ wt,
                 const float* __restrict__ bias, float* __restrict__ out) {
  __shared__ __align__(16) bf16 xt[HALO * HALO * CPAD];  // 46656 B

  const int b = blockIdx.z;
  const int x0 = blockIdx.x * TS;
  const int y0 = blockIdx.y * TS;
  const int tid = threadIdx.x;

  // ---- stage x tile (halo) fp32 -> bf16, [p = py*18+px][ci], pad 72 ----
  // task i = k*324 + p : ci-group k (8 ci), pixel p. Lanes take consecutive
  // p -> coalesced global reads; 16B LDS store, bank group (p+k)&7 -> free.
  for (int i = tid; i < 8 * HALO * HALO; i += 512) {
    const int k = i / (HALO * HALO);
    const int p = i - k * (HALO * HALO);
    const int py = p / HALO;
    const int px = p - py * HALO;
    const int gy = y0 + py - 1, gx = x0 + px - 1;
    bf16x8 v = {};
    if (gy >= 0 && gy < HH && gx >= 0 && gx < WW) {
      const float* xs = x + ((size_t)(b * CI + k * 8) * HH + gy) * WW + gx;
      #pragma unroll
      for (int j = 0; j < 8; ++j) v[j] = (bf16)xs[(size_t)j * HH * WW];
    }
    *reinterpret_cast<bf16x8*>(&xt[p * CPAD + k * 8]) = v;
  }

  const int lane = tid & 63;
  const int wv = tid >> 6;
  const int m = lane & 15;   // A row (co in group) / B col (pixel x)
  const int q = lane >> 4;   // quad
  const int cg = wv & 3;     // co group (16 co)
  const int ty0 = (wv >> 2) * 8;

  f32x4 acc[8];
  #pragma unroll
  for (int r = 0; r < 8; ++r) acc[r] = (f32x4){0.f, 0.f, 0.f, 0.f};

  // weight fragment base: rows co = cg*16 + m, 8 ci at kh*32 + q*8
  const bf16* wbase =
      wt + (size_t)b * 9 * CO * CI + (size_t)(cg * 16 + m) * CI + q * 8;

  bf16x8 a_cur0 = *reinterpret_cast<const bf16x8*>(wbase);
  bf16x8 a_cur1 = *reinterpret_cast<const bf16x8*>(wbase + 32);

  __syncthreads();  // xt ready

  #pragma unroll
  for (int tap = 0; tap < 9; ++tap) {
    bf16x8 a_n0 = a_cur0, a_n1 = a_cur1;
    if (tap < 8) {
      a_n0 = *reinterpret_cast<const bf16x8*>(wbase + (tap + 1) * CO * CI);
      a_n1 = *reinterpret_cast<const bf16x8*>(wbase + (tap + 1) * CO * CI + 32);
    }
    const int dy = tap / 3, dx = tap - dy * 3;
    const int pcol = m + dx;
    #pragma unroll
    for (int r = 0; r < 8; ++r) {
      const int p = (ty0 + r + dy) * HALO + pcol;
      bf16x8 bv0 = *reinterpret_cast<const bf16x8*>(&xt[p * CPAD + q * 8]);
      acc[r] = __builtin_amdgcn_mfma_f32_16x16x32_bf16(a_cur0, bv0, acc[r], 0, 0, 0);
    }
    #pragma unroll
    for (int r = 0; r < 8; ++r) {
      const int p = (ty0 + r + dy) * HALO + pcol;
      bf16x8 bv1 = *reinterpret_cast<const bf16x8*>(&xt[p * CPAD + 32 + q * 8]);
      acc[r] = __builtin_amdgcn_mfma_f32_16x16x32_bf16(a_cur1, bv1, acc[r], 0, 0, 0);
    }
    a_cur0 = a_n0;
    a_cur1 = a_n1;
  }

  // epilogue: C/D layout col = lane&15 (pixel x), row = q*4+reg (co in group)
  #pragma unroll
  for (int r = 0; r < 8; ++r) {
    const int gy = y0 + ty0 + r;
    #pragma unroll
    for (int rg = 0; rg < 4; ++rg) {
      const int co = cg * 16 + q * 4 + rg;
      float v = acc[r][rg] + bias[b * CO + co];
      out[((size_t)(b * CO + co) * HH + gy) * WW + x0 + m] = fmaxf(v, 0.f);
    }
  }
}

extern "C" void kernel_launch(void* const* d_in, const int* in_sizes, int n_in,
                              void* d_out, int out_size, void* d_ws,
                              size_t ws_size, hipStream_t stream) {
  const float* x = (const float*)d_in[0];
  const float* z = (const float*)d_in[1];
  const float* W0 = (const float*)d_in[2];
  const float* b0 = (const float*)d_in[3];
  const float* W1 = (const float*)d_in[4];
  const float* b1 = (const float*)d_in[5];
  const float* W2 = (const float*)d_in[6];
  const float* b2 = (const float*)d_in[7];
  float* out = (float*)d_out;

  // ws layout: wt bf16 [16][9][64][64] (1,179,648 B) | biases f32 [16][64]
  bf16* wt = (bf16*)d_ws;
  float* biases = (float*)((char*)d_ws + (size_t)NB * 9 * CO * CI * 2);

  hipLaunchKernelGGL(hyper_kernel, dim3(145), dim3(256), 0, stream,
                     z, W0, b0, W1, b1, W2, b2, wt, biases);
  hipLaunchKernelGGL(conv_kernel, dim3(WW / TS, HH / TS, NB), dim3(512), 0,
                     stream, x, wt, biases, out);
}

// Round 3
// 230.687 us; speedup vs baseline: 1.3997x; 1.3997x over previous
//
#include <hip/hip_runtime.h>

// AdaptiveConv2d: hypernetwork MLP -> per-sample conv kernels, then
// per-sample 3x3 SAME conv + bias + relu, via bf16 implicit-GEMM MFMA.
//
// R3 changes vs R2:
//  - conv: mfma 32x32x16 (2x FLOP per LDS byte), tile 32x8, wave = 1 output
//    row x 64 co (two 32-co tiles share each B fragment), acc = 32 VGPRs,
//    tap loop NOT unrolled (R2's full unroll caused scratch spills: 405 MB
//    WRITE_SIZE), weights per-lane from global (L1-hot), one barrier.
//  - hyper: unchanged from R2 (coalesced stores).

typedef __bf16 bf16;
typedef __bf16 bf16x8 __attribute__((ext_vector_type(8)));
typedef float f32x16 __attribute__((ext_vector_type(16)));

#define NB 16     // batch
#define CI 64
#define CO 64
#define HH 128
#define WW 128
#define TSX 32    // tile width
#define TSY 8     // tile height
#define HX 34     // TSX + 2
#define HY 10     // TSY + 2
#define NP (HX * HY)   // 340 halo pixels
#define CPAD 72   // xt ci stride (16B-aligned, even bank spread)
#define NKW 36864 // CO*CI*9

// ---------------- hypernetwork ----------------
// aw = relu(h1 @ W2^T + b2); emitted as wt[b][tap][co][ci] (bf16) + biases.
// Thread <-> output element e (ci fastest) so stores are coalesced; each
// thread reads its W2 row (30 floats) once, loops the 16 samples.
__global__ __launch_bounds__(256)
void hyper_kernel(const float* __restrict__ z, const float* __restrict__ W0,
                  const float* __restrict__ b0, const float* __restrict__ W1,
                  const float* __restrict__ b1, const float* __restrict__ W2,
                  const float* __restrict__ b2, bf16* __restrict__ wt,
                  float* __restrict__ biases) {
  __shared__ float h1s[NB][30];
  const int tid = threadIdx.x;
  if (tid < NB) {
    float h0[20];
    #pragma unroll
    for (int i = 0; i < 20; ++i) {
      float s = b0[i];
      #pragma unroll
      for (int j = 0; j < 16; ++j) s += W0[i * 16 + j] * z[tid * 16 + j];
      h0[i] = fmaxf(s, 0.f);
    }
    #pragma unroll
    for (int i = 0; i < 30; ++i) {
      float s = b1[i];
      #pragma unroll
      for (int j = 0; j < 20; ++j) s += W1[i * 20 + j] * h0[j];
      h1s[tid][i] = fmaxf(s, 0.f);
    }
  }
  __syncthreads();

  if (blockIdx.x < 144) {
    // kernel weights: e in [0, 36864), layout order (tap, co, ci)
    const int e = blockIdx.x * 256 + tid;
    const int tap = e >> 12;
    const int rem = e & 4095;
    const int co = rem >> 6;
    const int ci = rem & 63;
    const int r = co * 576 + ci * 9 + tap;  // W2 row
    float w2r[30];
    #pragma unroll
    for (int j = 0; j < 30; ++j) w2r[j] = W2[r * 30 + j];
    const float bb = b2[r];
    for (int b = 0; b < NB; ++b) {
      float s = bb;
      #pragma unroll
      for (int j = 0; j < 30; ++j) s += w2r[j] * h1s[b][j];
      wt[(size_t)b * NKW + e] = (bf16)fmaxf(s, 0.f);
    }
  } else {
    if (tid < CO) {
      const int r = NKW + tid;
      float w2r[30];
      #pragma unroll
      for (int j = 0; j < 30; ++j) w2r[j] = W2[r * 30 + j];
      const float bb = b2[r];
      for (int b = 0; b < NB; ++b) {
        float s = bb;
        #pragma unroll
        for (int j = 0; j < 30; ++j) s += w2r[j] * h1s[b][j];
        biases[b * CO + tid] = fmaxf(s, 0.f);
      }
    }
  }
}

// ---------------- conv (implicit GEMM, 32x32x16 bf16 MFMA) ----------------
// block: 1 sample x 32x8 spatial tile x all 64 co, 512 threads = 8 waves.
// Wave wv handles output row y0+wv (n = 32 px) and BOTH 32-co tiles, so each
// B fragment feeds 2 MFMAs. K = 9 taps x 64 ci (4 k-steps of 16 per tap).
// A (weights) stream per-lane from global: 8 KB/tap/sample, L1-resident.
__global__ __launch_bounds__(512)
void conv_kernel(const float* __restrict__ x, const bf16* __restrict__ wt,
                 const float* __restrict__ bias, float* __restrict__ out) {
  __shared__ __align__(16) bf16 xt[NP * CPAD];  // 48960 B

  const int b = blockIdx.z;
  const int x0 = blockIdx.x * TSX;
  const int y0 = blockIdx.y * TSY;
  const int tid = threadIdx.x;

  // ---- stage x tile (halo 34x10) fp32 -> bf16, layout [p][ci] pad 72 ----
  // task i = k*NP + p: ci-group k (8 ci), pixel p; lanes take consecutive p
  // -> coalesced global reads, one 16B LDS store per task.
  for (int i = tid; i < 8 * NP; i += 512) {
    const int k = i / NP;
    const int p = i - k * NP;
    const int py = p / HX;
    const int px = p - py * HX;
    const int gy = y0 + py - 1, gx = x0 + px - 1;
    bf16x8 v = {};
    if (gy >= 0 && gy < HH && gx >= 0 && gx < WW) {
      const float* xs = x + ((size_t)(b * CI + k * 8) * HH + gy) * WW + gx;
      #pragma unroll
      for (int j = 0; j < 8; ++j) v[j] = (bf16)xs[(size_t)j * HH * WW];
    }
    *reinterpret_cast<bf16x8*>(&xt[p * CPAD + k * 8]) = v;
  }

  const int lane = tid & 63;
  const int wv = tid >> 6;     // output row within tile
  const int n = lane & 31;     // px (B col) / co-in-tile (A row)
  const int half = lane >> 5;  // k-half: k = half*8 + j

  f32x16 acc0 = {};  // co 0..31
  f32x16 acc1 = {};  // co 32..63

  // lane's A rows: co = n (+32 for tile 1); ci offset half*8 (+ s*16)
  const bf16* wl = wt + (size_t)b * 9 * CO * CI + (size_t)n * CI + half * 8;

  __syncthreads();  // xt ready

  int dy = 0, dx = 0;
  #pragma unroll 1
  for (int tap = 0; tap < 9; ++tap) {
    const bf16* wl1 = wl + 32 * CI;
    const bf16* xp = &xt[((wv + dy) * HX + n + dx) * CPAD + half * 8];
    #pragma unroll
    for (int s = 0; s < 4; ++s) {
      bf16x8 a0 = *reinterpret_cast<const bf16x8*>(wl + s * 16);
      bf16x8 a1 = *reinterpret_cast<const bf16x8*>(wl1 + s * 16);
      bf16x8 bv = *reinterpret_cast<const bf16x8*>(xp + s * 16);
      acc0 = __builtin_amdgcn_mfma_f32_32x32x16_bf16(a0, bv, acc0, 0, 0, 0);
      acc1 = __builtin_amdgcn_mfma_f32_32x32x16_bf16(a1, bv, acc1, 0, 0, 0);
    }
    wl += CO * CI;
    if (++dx == 3) { dx = 0; ++dy; }
  }

  // epilogue: C/D col = lane&31 (px), row = (r&3) + 8*(r>>2) + 4*half (co)
  const int gy = y0 + wv;
  #pragma unroll
  for (int t = 0; t < 2; ++t) {
    #pragma unroll
    for (int r = 0; r < 16; ++r) {
      const int co = t * 32 + (r & 3) + 8 * (r >> 2) + 4 * half;
      const float a = t ? acc1[r] : acc0[r];
      const float v = a + bias[b * CO + co];
      out[((size_t)(b * CO + co) * HH + gy) * WW + x0 + n] = fmaxf(v, 0.f);
    }
  }
}

extern "C" void kernel_launch(void* const* d_in, const int* in_sizes, int n_in,
                              void* d_out, int out_size, void* d_ws,
                              size_t ws_size, hipStream_t stream) {
  const float* x = (const float*)d_in[0];
  const float* z = (const float*)d_in[1];
  const float* W0 = (const float*)d_in[2];
  const float* b0 = (const float*)d_in[3];
  const float* W1 = (const float*)d_in[4];
  const float* b1 = (const float*)d_in[5];
  const float* W2 = (const float*)d_in[6];
  const float* b2 = (const float*)d_in[7];
  float* out = (float*)d_out;

  // ws layout: wt bf16 [16][9][64][64] (1,179,648 B) | biases f32 [16][64]
  bf16* wt = (bf16*)d_ws;
  float* biases = (float*)((char*)d_ws + (size_t)NB * 9 * CO * CI * 2);

  hipLaunchKernelGGL(hyper_kernel, dim3(145), dim3(256), 0, stream,
                     z, W0, b0, W1, b1, W2, b2, wt, biases);
  hipLaunchKernelGGL(conv_kernel, dim3(WW / TSX, HH / TSY, NB), dim3(512), 0,
                     stream, x, wt, biases, out);
}

// Round 4
// 220.276 us; speedup vs baseline: 1.4658x; 1.0473x over previous
//
#include <hip/hip_runtime.h>

// AdaptiveConv2d: hypernetwork MLP -> per-sample conv kernels, then
// per-sample 3x3 SAME conv + bias + relu, via bf16 implicit-GEMM MFMA.
//
// R4 changes vs R3 (all latency-targeted; R3 was idle on every pipe):
//  - conv: 32x4 tile / 256 thr / 29 KB LDS (4-5 blocks/CU, 2048 blocks);
//    staging software-pipelined (load i+1 while storing i); next-tap
//    weight fragments prefetched into a 2nd register set.
//  - hyper split: permute kernel makes e-ordered 32-float W2 rows
//    (coalesced read+write), hyper loads its slab coalesced into LDS
//    (row pad 33) -> fully coalesced reads AND stores.

typedef __bf16 bf16;
typedef __bf16 bf16x8 __attribute__((ext_vector_type(8)));
typedef float f32x16 __attribute__((ext_vector_type(16)));

#define NB 16
#define CI 64
#define CO 64
#define HH 128
#define WW 128
#define TSX 32
#define TSY 4
#define HX 34        // TSX + 2
#define HY 6         // TSY + 2
#define NP (HX * HY) // 204 halo pixels
#define NTASK (8 * NP)
#define CPAD 72      // xt ci stride (16B-aligned, bank-spread)
#define NKW 36864
#define NROWS 36928

// ---------------- permute: W2 rows -> e-order, 32-float rows ----------------
// wp[e][0..29] = W2[r(e)][:], wp[e][30] = b2[r(e)], wp[e][31] = 0.
// thread <-> (r, j): reads coalesced over W2, writes 128B row chunks.
__global__ __launch_bounds__(256)
void permute_kernel(const float* __restrict__ W2, const float* __restrict__ b2,
                    float* __restrict__ wp) {
  const int idx = blockIdx.x * 256 + threadIdx.x;
  if (idx >= NROWS * 32) return;
  const int r = idx >> 5;
  const int j = idx & 31;
  float v = 0.f;
  if (j < 30) v = W2[r * 30 + j];
  else if (j == 30) v = b2[r];
  int e;
  if (r < NKW) {
    const int co = r / 576;
    const int rem = r - co * 576;
    const int ci = rem / 9;
    const int tap = rem - ci * 9;
    e = tap * 4096 + co * 64 + ci;
  } else {
    e = r;  // bias rows keep their index
  }
  wp[(size_t)e * 32 + j] = v;
}

// ---------------- hypernetwork ----------------
// block <-> 256 consecutive e. Slab of wp loaded coalesced into LDS
// (pad rows to 33 floats: stride 33 = conflict-free reads). Stores coalesced.
__global__ __launch_bounds__(256)
void hyper_kernel(const float* __restrict__ z, const float* __restrict__ W0,
                  const float* __restrict__ b0, const float* __restrict__ W1,
                  const float* __restrict__ b1, const float* __restrict__ wp,
                  bf16* __restrict__ wt, float* __restrict__ biases) {
  __shared__ float h1s[NB][30];
  __shared__ float slab[256 * 33];  // 33 KB
  const int tid = threadIdx.x;
  const int e0 = blockIdx.x * 256;
  const int nrows = min(256, NROWS - e0);

  for (int i = tid; i < nrows * 32; i += 256)
    slab[(i >> 5) * 33 + (i & 31)] = wp[(size_t)e0 * 32 + i];

  if (tid < NB) {
    float h0[20];
    #pragma unroll
    for (int i = 0; i < 20; ++i) {
      float s = b0[i];
      #pragma unroll
      for (int j = 0; j < 16; ++j) s += W0[i * 16 + j] * z[tid * 16 + j];
      h0[i] = fmaxf(s, 0.f);
    }
    #pragma unroll
    for (int i = 0; i < 30; ++i) {
      float s = b1[i];
      #pragma unroll
      for (int j = 0; j < 20; ++j) s += W1[i * 20 + j] * h0[j];
      h1s[tid][i] = fmaxf(s, 0.f);
    }
  }
  __syncthreads();

  if (tid < nrows) {
    const int e = e0 + tid;
    float w2r[30];
    #pragma unroll
    for (int j = 0; j < 30; ++j) w2r[j] = slab[tid * 33 + j];
    const float bb = slab[tid * 33 + 30];
    for (int b = 0; b < NB; ++b) {
      float s = bb;
      #pragma unroll
      for (int j = 0; j < 30; ++j) s += w2r[j] * h1s[b][j];
      s = fmaxf(s, 0.f);
      if (e < NKW)
        wt[(size_t)b * NKW + e] = (bf16)s;
      else
        biases[b * CO + (e - NKW)] = s;
    }
  }
}

// ---------------- conv (implicit GEMM, 32x32x16 bf16 MFMA) ----------------
// block: 1 sample x 32x4 tile x all 64 co, 256 threads = 4 waves.
// Wave wv: output row y0+wv, both 32-co tiles (each B fragment -> 2 MFMAs).
// Weights: per-lane from global (L2-hot), next tap prefetched into wB.
__global__ __launch_bounds__(256)
void conv_kernel(const float* __restrict__ x, const bf16* __restrict__ wt,
                 const float* __restrict__ bias, float* __restrict__ out) {
  __shared__ __align__(16) bf16 xt[NP * CPAD];  // 29376 B

  const int b = blockIdx.z;
  const int x0 = blockIdx.x * TSX;
  const int y0 = blockIdx.y * TSY;
  const int tid = threadIdx.x;

  // ---- staging: [p][ci] bf16, pad 72; 2-deep software pipeline ----
  // task i = k*NP + p: ci-group k (8 ci), pixel p; lanes take consecutive p
  // -> coalesced 4B global loads, one 16B LDS store per task.
  {
    float cur[8], nxt[8];
    int i = tid;
    {
      const int k = i / NP;
      const int p = i - k * NP;
      const int py = p / HX;
      const int px = p - py * HX;
      const int gy = y0 + py - 1, gx = x0 + px - 1;
      const bool ok = (gy >= 0 && gy < HH && gx >= 0 && gx < WW);
      const float* xs = x + ((size_t)(b * CI + k * 8) * HH + gy) * WW + gx;
      #pragma unroll
      for (int j = 0; j < 8; ++j) cur[j] = ok ? xs[(size_t)j * HH * WW] : 0.f;
    }
    while (i < NTASK) {
      const int in = i + 256;
      if (in < NTASK) {
        const int k = in / NP;
        const int p = in - k * NP;
        const int py = p / HX;
        const int px = p - py * HX;
        const int gy = y0 + py - 1, gx = x0 + px - 1;
        const bool ok = (gy >= 0 && gy < HH && gx >= 0 && gx < WW);
        const float* xs = x + ((size_t)(b * CI + k * 8) * HH + gy) * WW + gx;
        #pragma unroll
        for (int j = 0; j < 8; ++j) nxt[j] = ok ? xs[(size_t)j * HH * WW] : 0.f;
      }
      {
        const int k = i / NP;
        const int p = i - k * NP;
        bf16x8 o;
        #pragma unroll
        for (int j = 0; j < 8; ++j) o[j] = (bf16)cur[j];
        *reinterpret_cast<bf16x8*>(&xt[p * CPAD + k * 8]) = o;
      }
      #pragma unroll
      for (int j = 0; j < 8; ++j) cur[j] = nxt[j];
      i = in;
    }
  }

  const int lane = tid & 63;
  const int wv = tid >> 6;     // output row within tile (0..3)
  const int n = lane & 31;     // px (B col) / co-in-tile (A row)
  const int half = lane >> 5;  // k-half: k = half*8 + j

  f32x16 acc0 = {};  // co 0..31
  f32x16 acc1 = {};  // co 32..63

  const bf16* wl = wt + (size_t)b * 9 * CO * CI + (size_t)n * CI + half * 8;

  // preload tap 0 fragments: wA[2s] = co-tile0, wA[2s+1] = co-tile1
  bf16x8 wA[8];
  #pragma unroll
  for (int s = 0; s < 4; ++s) {
    wA[2 * s]     = *reinterpret_cast<const bf16x8*>(wl + s * 16);
    wA[2 * s + 1] = *reinterpret_cast<const bf16x8*>(wl + 32 * CI + s * 16);
  }

  __syncthreads();  // xt ready

  #pragma unroll 1
  for (int tap = 0; tap < 9; ++tap) {
    // prefetch next tap's fragments first (hidden behind this tap's MFMAs)
    bf16x8 wB[8];
    const bf16* wn = wl + (size_t)(tap + 1) * CO * CI;
    if (tap < 8) {
      #pragma unroll
      for (int s = 0; s < 4; ++s) {
        wB[2 * s]     = *reinterpret_cast<const bf16x8*>(wn + s * 16);
        wB[2 * s + 1] = *reinterpret_cast<const bf16x8*>(wn + 32 * CI + s * 16);
      }
    }
    const int dy = tap / 3, dx = tap - dy * 3;
    const bf16* xp = &xt[((wv + dy) * HX + n + dx) * CPAD + half * 8];
    #pragma unroll
    for (int s = 0; s < 4; ++s) {
      bf16x8 bv = *reinterpret_cast<const bf16x8*>(xp + s * 16);
      acc0 = __builtin_amdgcn_mfma_f32_32x32x16_bf16(wA[2 * s], bv, acc0, 0, 0, 0);
      acc1 = __builtin_amdgcn_mfma_f32_32x32x16_bf16(wA[2 * s + 1], bv, acc1, 0, 0, 0);
    }
    if (tap < 8) {
      #pragma unroll
      for (int s = 0; s < 8; ++s) wA[s] = wB[s];
    }
  }

  // epilogue: C/D col = lane&31 (px), row = (r&3) + 8*(r>>2) + 4*half (co)
  const int gy = y0 + wv;
  #pragma unroll
  for (int t = 0; t < 2; ++t) {
    #pragma unroll
    for (int r = 0; r < 16; ++r) {
      const int co = t * 32 + (r & 3) + 8 * (r >> 2) + 4 * half;
      const float a = t ? acc1[r] : acc0[r];
      const float v = a + bias[b * CO + co];
      out[((size_t)(b * CO + co) * HH + gy) * WW + x0 + n] = fmaxf(v, 0.f);
    }
  }
}

extern "C" void kernel_launch(void* const* d_in, const int* in_sizes, int n_in,
                              void* d_out, int out_size, void* d_ws,
                              size_t ws_size, hipStream_t stream) {
  const float* x = (const float*)d_in[0];
  const float* z = (const float*)d_in[1];
  const float* W0 = (const float*)d_in[2];
  const float* b0 = (const float*)d_in[3];
  const float* W1 = (const float*)d_in[4];
  const float* b1 = (const float*)d_in[5];
  const float* W2 = (const float*)d_in[6];
  const float* b2 = (const float*)d_in[7];
  float* out = (float*)d_out;

  // ws: wt bf16 [16][9][64][64] (1,179,648 B) | biases f32 [16][64] (4 KB)
  //     | wp f32 [36928][32] (4,726,784 B)
  bf16* wt = (bf16*)d_ws;
  float* biases = (float*)((char*)d_ws + (size_t)NB * 9 * CO * CI * 2);
  float* wp = (float*)((char*)d_ws + (size_t)NB * 9 * CO * CI * 2 + 4096);

  hipLaunchKernelGGL(permute_kernel, dim3((NROWS * 32 + 255) / 256), dim3(256),
                     0, stream, W2, b2, wp);
  hipLaunchKernelGGL(hyper_kernel, dim3((NROWS + 255) / 256), dim3(256), 0,
                     stream, z, W0, b0, W1, b1, wp, wt, biases);
  hipLaunchKernelGGL(conv_kernel, dim3(WW / TSX, HH / TSY, NB), dim3(256), 0,
                     stream, x, wt, biases, out);
}

// Round 5
// 201.950 us; speedup vs baseline: 1.5988x; 1.0907x over previous
//
#include <hip/hip_runtime.h>

// AdaptiveConv2d: hypernetwork MLP -> per-sample conv kernels, then
// per-sample 3x3 SAME conv + bias + relu, via bf16 implicit-GEMM MFMA.
//
// R5 changes vs R4 (conv only; hyper/permute unchanged):
//  - wave = 2 output rows x 64 co (4 accumulators): 16 MFMAs per 8-weight
//    load round (was 8), A fragments reused across rows -> weight latency
//    covered by ~3 waves/SIMD instead of stalling each wave 240 cyc/tap.
//  - tile 32x8 / 256 thr / 49 KB LDS -> 3 blocks/CU, grid 1024.

typedef __bf16 bf16;
typedef __bf16 bf16x8 __attribute__((ext_vector_type(8)));
typedef float f32x16 __attribute__((ext_vector_type(16)));

#define NB 16
#define CI 64
#define CO 64
#define HH 128
#define WW 128
#define TSX 32
#define TSY 8
#define HX 34        // TSX + 2
#define HY 10        // TSY + 2
#define NP (HX * HY) // 340 halo pixels
#define NTASK (8 * NP)
#define CPAD 72      // xt ci stride (16B-aligned, bank-spread)
#define NKW 36864
#define NROWS 36928

// ---------------- permute: W2 rows -> e-order, 32-float rows ----------------
__global__ __launch_bounds__(256)
void permute_kernel(const float* __restrict__ W2, const float* __restrict__ b2,
                    float* __restrict__ wp) {
  const int idx = blockIdx.x * 256 + threadIdx.x;
  if (idx >= NROWS * 32) return;
  const int r = idx >> 5;
  const int j = idx & 31;
  float v = 0.f;
  if (j < 30) v = W2[r * 30 + j];
  else if (j == 30) v = b2[r];
  int e;
  if (r < NKW) {
    const int co = r / 576;
    const int rem = r - co * 576;
    const int ci = rem / 9;
    const int tap = rem - ci * 9;
    e = tap * 4096 + co * 64 + ci;
  } else {
    e = r;
  }
  wp[(size_t)e * 32 + j] = v;
}

// ---------------- hypernetwork ----------------
__global__ __launch_bounds__(256)
void hyper_kernel(const float* __restrict__ z, const float* __restrict__ W0,
                  const float* __restrict__ b0, const float* __restrict__ W1,
                  const float* __restrict__ b1, const float* __restrict__ wp,
                  bf16* __restrict__ wt, float* __restrict__ biases) {
  __shared__ float h1s[NB][30];
  __shared__ float slab[256 * 33];  // 33 KB
  const int tid = threadIdx.x;
  const int e0 = blockIdx.x * 256;
  const int nrows = min(256, NROWS - e0);

  for (int i = tid; i < nrows * 32; i += 256)
    slab[(i >> 5) * 33 + (i & 31)] = wp[(size_t)e0 * 32 + i];

  if (tid < NB) {
    float h0[20];
    #pragma unroll
    for (int i = 0; i < 20; ++i) {
      float s = b0[i];
      #pragma unroll
      for (int j = 0; j < 16; ++j) s += W0[i * 16 + j] * z[tid * 16 + j];
      h0[i] = fmaxf(s, 0.f);
    }
    #pragma unroll
    for (int i = 0; i < 30; ++i) {
      float s = b1[i];
      #pragma unroll
      for (int j = 0; j < 20; ++j) s += W1[i * 20 + j] * h0[j];
      h1s[tid][i] = fmaxf(s, 0.f);
    }
  }
  __syncthreads();

  if (tid < nrows) {
    const int e = e0 + tid;
    float w2r[30];
    #pragma unroll
    for (int j = 0; j < 30; ++j) w2r[j] = slab[tid * 33 + j];
    const float bb = slab[tid * 33 + 30];
    for (int b = 0; b < NB; ++b) {
      float s = bb;
      #pragma unroll
      for (int j = 0; j < 30; ++j) s += w2r[j] * h1s[b][j];
      s = fmaxf(s, 0.f);
      if (e < NKW)
        wt[(size_t)b * NKW + e] = (bf16)s;
      else
        biases[b * CO + (e - NKW)] = s;
    }
  }
}

// ---------------- conv (implicit GEMM, 32x32x16 bf16 MFMA) ----------------
// block: 1 sample x 32x8 tile x all 64 co, 256 threads = 4 waves.
// Wave wv: output rows {2wv, 2wv+1}, both 32-co tiles. Per tap: 8 weight
// fragment loads (reused across both rows), 8 B ds_reads, 16 MFMAs.
// Next-tap weights prefetched into wB. One barrier per block.
__global__ __launch_bounds__(256)
void conv_kernel(const float* __restrict__ x, const bf16* __restrict__ wt,
                 const float* __restrict__ bias, float* __restrict__ out) {
  __shared__ __align__(16) bf16 xt[NP * CPAD];  // 48960 B

  const int b = blockIdx.z;
  const int x0 = blockIdx.x * TSX;
  const int y0 = blockIdx.y * TSY;
  const int tid = threadIdx.x;

  // ---- staging: [p][ci] bf16, pad 72; 2-deep software pipeline ----
  {
    float cur[8], nxt[8];
    int i = tid;
    {
      const int k = i / NP;
      const int p = i - k * NP;
      const int py = p / HX;
      const int px = p - py * HX;
      const int gy = y0 + py - 1, gx = x0 + px - 1;
      const bool ok = (gy >= 0 && gy < HH && gx >= 0 && gx < WW);
      const float* xs = x + ((size_t)(b * CI + k * 8) * HH + gy) * WW + gx;
      #pragma unroll
      for (int j = 0; j < 8; ++j) cur[j] = ok ? xs[(size_t)j * HH * WW] : 0.f;
    }
    while (i < NTASK) {
      const int in = i + 256;
      if (in < NTASK) {
        const int k = in / NP;
        const int p = in - k * NP;
        const int py = p / HX;
        const int px = p - py * HX;
        const int gy = y0 + py - 1, gx = x0 + px - 1;
        const bool ok = (gy >= 0 && gy < HH && gx >= 0 && gx < WW);
        const float* xs = x + ((size_t)(b * CI + k * 8) * HH + gy) * WW + gx;
        #pragma unroll
        for (int j = 0; j < 8; ++j) nxt[j] = ok ? xs[(size_t)j * HH * WW] : 0.f;
      }
      {
        const int k = i / NP;
        const int p = i - k * NP;
        bf16x8 o;
        #pragma unroll
        for (int j = 0; j < 8; ++j) o[j] = (bf16)cur[j];
        *reinterpret_cast<bf16x8*>(&xt[p * CPAD + k * 8]) = o;
      }
      #pragma unroll
      for (int j = 0; j < 8; ++j) cur[j] = nxt[j];
      i = in;
    }
  }

  const int lane = tid & 63;
  const int wv = tid >> 6;     // row pair (0..3) -> rows 2wv, 2wv+1
  const int n = lane & 31;     // px (B col) / co-in-tile (A row)
  const int half = lane >> 5;  // k-half: k = half*8 + j

  f32x16 acc00 = {};  // row0, co 0..31
  f32x16 acc01 = {};  // row1, co 0..31
  f32x16 acc10 = {};  // row0, co 32..63
  f32x16 acc11 = {};  // row1, co 32..63

  const bf16* wl = wt + (size_t)b * 9 * CO * CI + (size_t)n * CI + half * 8;

  // preload tap 0 fragments: wA[2s] = co-tile0, wA[2s+1] = co-tile1
  bf16x8 wA[8];
  #pragma unroll
  for (int s = 0; s < 4; ++s) {
    wA[2 * s]     = *reinterpret_cast<const bf16x8*>(wl + s * 16);
    wA[2 * s + 1] = *reinterpret_cast<const bf16x8*>(wl + 32 * CI + s * 16);
  }

  __syncthreads();  // xt ready

  #pragma unroll 1
  for (int tap = 0; tap < 9; ++tap) {
    bf16x8 wB[8];
    const bf16* wn = wl + (size_t)(tap + 1) * CO * CI;
    if (tap < 8) {
      #pragma unroll
      for (int s = 0; s < 4; ++s) {
        wB[2 * s]     = *reinterpret_cast<const bf16x8*>(wn + s * 16);
        wB[2 * s + 1] = *reinterpret_cast<const bf16x8*>(wn + 32 * CI + s * 16);
      }
    }
    const int dy = tap / 3, dx = tap - dy * 3;
    const bf16* xp0 = &xt[((2 * wv + dy) * HX + n + dx) * CPAD + half * 8];
    const bf16* xp1 = xp0 + HX * CPAD;  // next output row
    #pragma unroll
    for (int s = 0; s < 4; ++s) {
      bf16x8 bv0 = *reinterpret_cast<const bf16x8*>(xp0 + s * 16);
      bf16x8 bv1 = *reinterpret_cast<const bf16x8*>(xp1 + s * 16);
      acc00 = __builtin_amdgcn_mfma_f32_32x32x16_bf16(wA[2 * s], bv0, acc00, 0, 0, 0);
      acc01 = __builtin_amdgcn_mfma_f32_32x32x16_bf16(wA[2 * s], bv1, acc01, 0, 0, 0);
      acc10 = __builtin_amdgcn_mfma_f32_32x32x16_bf16(wA[2 * s + 1], bv0, acc10, 0, 0, 0);
      acc11 = __builtin_amdgcn_mfma_f32_32x32x16_bf16(wA[2 * s + 1], bv1, acc11, 0, 0, 0);
    }
    if (tap < 8) {
      #pragma unroll
      for (int s = 0; s < 8; ++s) wA[s] = wB[s];
    }
  }

  // epilogue: C/D col = lane&31 (px), row = (r&3) + 8*(r>>2) + 4*half (co)
  #pragma unroll
  for (int r2 = 0; r2 < 2; ++r2) {
    const int gy = y0 + 2 * wv + r2;
    #pragma unroll
    for (int t = 0; t < 2; ++t) {
      #pragma unroll
      for (int r = 0; r < 16; ++r) {
        const int co = t * 32 + (r & 3) + 8 * (r >> 2) + 4 * half;
        const f32x16& a = r2 ? (t ? acc11 : acc01) : (t ? acc10 : acc00);
        const float v = a[r] + bias[b * CO + co];
        out[((size_t)(b * CO + co) * HH + gy) * WW + x0 + n] = fmaxf(v, 0.f);
      }
    }
  }
}

extern "C" void kernel_launch(void* const* d_in, const int* in_sizes, int n_in,
                              void* d_out, int out_size, void* d_ws,
                              size_t ws_size, hipStream_t stream) {
  const float* x = (const float*)d_in[0];
  const float* z = (const float*)d_in[1];
  const float* W0 = (const float*)d_in[2];
  const float* b0 = (const float*)d_in[3];
  const float* W1 = (const float*)d_in[4];
  const float* b1 = (const float*)d_in[5];
  const float* W2 = (const float*)d_in[6];
  const float* b2 = (const float*)d_in[7];
  float* out = (float*)d_out;

  // ws: wt bf16 [16][9][64][64] (1,179,648 B) | biases f32 [16][64] (4 KB)
  //     | wp f32 [36928][32] (4,726,784 B)
  bf16* wt = (bf16*)d_ws;
  float* biases = (float*)((char*)d_ws + (size_t)NB * 9 * CO * CI * 2);
  float* wp = (float*)((char*)d_ws + (size_t)NB * 9 * CO * CI * 2 + 4096);

  hipLaunchKernelGGL(permute_kernel, dim3((NROWS * 32 + 255) / 256), dim3(256),
                     0, stream, W2, b2, wp);
  hipLaunchKernelGGL(hyper_kernel, dim3((NROWS + 255) / 256), dim3(256), 0,
                     stream, z, W0, b0, W1, b1, wp, wt, biases);
  hipLaunchKernelGGL(conv_kernel, dim3(WW / TSX, HH / TSY, NB), dim3(256), 0,
                     stream, x, wt, biases, out);
}